// Round 20
// baseline (35226.385 us; speedup 1.0000x reference)
//
#include <hip/hip_runtime.h>
#include <stdio.h>

#define NN 20000
#define NE 640000
#define NL 10

typedef unsigned short u16;
typedef unsigned int u32;

__device__ float bf2f(u16 u) {
  u32 x = ((u32)u) << 16;
  return __uint_as_float(x);
}
__device__ u16 f2bf(float f) {
  u32 x = __float_as_uint(f);
  u32 r = (x + 0x7fffu + ((x >> 16) & 1u)) >> 16;
  return (u16)r;
}

// stub-named kernel retained (inert).
__global__ void LearnedSimModel_28716151341396_kernel() {}

__global__ void init_kernel(float* agg, int agg_n) {
  int i = blockIdx.x * 256 + threadIdx.x;
  if (i < agg_n) agg[i] = 0.0f;
}

// edge_index: reference says int64; detect and handle int32 too.
__global__ void idx_detect_kernel(const int* raw, int* flag) {
  if (threadIdx.x == 0 && blockIdx.x == 0) {
    int any = 0;
    for (int k = 0; k < 16; ++k) any = any | raw[2 * k + 1];
    flag[0] = (any != 0) ? 1 : 0;  // 1 -> int32 storage
  }
}

__global__ void idx_prep_kernel(const int* raw, const int* flag, int* idx) {
  int i = blockIdx.x * 256 + threadIdx.x;
  if (i < 2 * NE) {
    int v;
    if (flag[0] != 0) {
      v = raw[i];
    } else {
      long long w = ((const long long*)raw)[i];
      v = (int)w;
    }
    if (v < 0) v = 0;
    if (v >= NN) v = NN - 1;
    idx[i] = v;
  }
}

// node encoder: h[n,:] = mlp16(x[n,:]+noise[n,:]) ; one block (128 thr) per node
__global__ void node_enc_kernel(const float* x, const float* noise,
                                const float* w1, const float* b1,
                                const float* w2, const float* b2,
                                float* h) {
  __shared__ float in16[16];
  __shared__ float t1s[128];
  int f = threadIdx.x;
  int n = blockIdx.x;
  if (f < 16) in16[f] = x[n * 16 + f] + noise[n * 16 + f];
  __syncthreads();
  float a = b1[f];
  for (int k = 0; k < 16; ++k) a += in16[k] * w1[k * 128 + f];
  t1s[f] = fmaxf(a, 0.0f);
  __syncthreads();
  float o = b2[f];
  for (int k = 0; k < 128; ++k) o += t1s[k] * w2[k * 128 + f];
  h[(long long)n * 128 + f] = o;
}

// edge encoder: e[i,:] = mlp8(attr[i,:]+noise[i,:]) ; e stored bf16
__global__ void edge_enc_kernel(const float* attr, const float* noise,
                                const float* w1, const float* b1,
                                const float* w2, const float* b2,
                                u16* e) {
  __shared__ float in8[8];
  __shared__ float t1s[128];
  int f = threadIdx.x;
  int n = blockIdx.x;
  if (f < 8) in8[f] = attr[n * 8 + f] + noise[n * 8 + f];
  __syncthreads();
  float a = b1[f];
  for (int k = 0; k < 8; ++k) a += in8[k] * w1[k * 128 + f];
  t1s[f] = fmaxf(a, 0.0f);
  __syncthreads();
  float o = b2[f];
  for (int k = 0; k < 128; ++k) o += t1s[k] * w2[k * 128 + f];
  e[(long long)n * 128 + f] = f2bf(o);
}

// fused GNN edge kernel: 4 edges per block, 128 threads (thread = feature f)
__global__ void gnn_edge_kernel(const float* h, u16* e,
                                const int* src, const int* dst,
                                const float* we1, const float* be1,
                                const float* we2, const float* be2,
                                const float* wn1, const float* bn1,
                                const float* wn2, const float* bn2,
                                const float* lng, const float* lnb,
                                float* agg) {
  __shared__ float cat[4][384];   // [xi | xj | e] per edge
  __shared__ float t1s[4][128];
  __shared__ float ens[4][128];   // e_new
  __shared__ float t2s[4][128];
  __shared__ float red[128];

  int f = threadIdx.x;
  int e0 = blockIdx.x * 4;

  for (int ed = 0; ed < 4; ++ed) {
    int de = dst[e0 + ed];
    int se = src[e0 + ed];
    cat[ed][f]       = h[(long long)de * 128 + f];   // xi
    cat[ed][128 + f] = h[(long long)se * 128 + f];   // xj
    cat[ed][256 + f] = bf2f(e[(long long)(e0 + ed) * 128 + f]);
  }
  __syncthreads();

  // GEMM1: t1 = relu([xi|xj|e] @ We1 + be1), K = 384
  float a0 = 0.0f, a1 = 0.0f, a2 = 0.0f, a3 = 0.0f;
  for (int k = 0; k < 384; ++k) {
    float w = we1[k * 128 + f];
    a0 += cat[0][k] * w;
    a1 += cat[1][k] * w;
    a2 += cat[2][k] * w;
    a3 += cat[3][k] * w;
  }
  {
    float b = be1[f];
    t1s[0][f] = fmaxf(a0 + b, 0.0f);
    t1s[1][f] = fmaxf(a1 + b, 0.0f);
    t1s[2][f] = fmaxf(a2 + b, 0.0f);
    t1s[3][f] = fmaxf(a3 + b, 0.0f);
  }
  __syncthreads();

  // GEMM2: e_new = e + t1 @ We2 + be2
  a0 = 0.0f; a1 = 0.0f; a2 = 0.0f; a3 = 0.0f;
  for (int k = 0; k < 128; ++k) {
    float w = we2[k * 128 + f];
    a0 += t1s[0][k] * w;
    a1 += t1s[1][k] * w;
    a2 += t1s[2][k] * w;
    a3 += t1s[3][k] * w;
  }
  {
    float b = be2[f];
    ens[0][f] = cat[0][256 + f] + a0 + b;
    ens[1][f] = cat[1][256 + f] + a1 + b;
    ens[2][f] = cat[2][256 + f] + a2 + b;
    ens[3][f] = cat[3][256 + f] + a3 + b;
  }
  __syncthreads();

  // e-LayerNorm: e = LN(e + e_new)
  {
    float gf = lng[f];
    float bfv = lnb[f];
    for (int ed = 0; ed < 4; ++ed) {
      float lnv = cat[ed][256 + f] + ens[ed][f];
      red[f] = lnv;
      __syncthreads();
      for (int s = 64; s > 0; s >>= 1) {
        if (f < s) red[f] += red[f + s];
        __syncthreads();
      }
      float m = red[0] * (1.0f / 128.0f);
      __syncthreads();
      red[f] = lnv * lnv;
      __syncthreads();
      for (int s = 64; s > 0; s >>= 1) {
        if (f < s) red[f] += red[f + s];
        __syncthreads();
      }
      float q = red[0] * (1.0f / 128.0f);
      __syncthreads();
      float var = q - m * m;
      float rs = rsqrtf(fmaxf(var, 0.0f) + 1e-5f);
      e[(long long)(e0 + ed) * 128 + f] = f2bf((lnv - m) * rs * gf + bfv);
    }
  }

  // GEMM3: t2 = relu([xi|e_new] @ Wn1 + bn1), K = 256
  a0 = 0.0f; a1 = 0.0f; a2 = 0.0f; a3 = 0.0f;
  for (int k = 0; k < 128; ++k) {
    float w = wn1[k * 128 + f];
    a0 += cat[0][k] * w;
    a1 += cat[1][k] * w;
    a2 += cat[2][k] * w;
    a3 += cat[3][k] * w;
  }
  for (int k = 0; k < 128; ++k) {
    float w = wn1[(128 + k) * 128 + f];
    a0 += ens[0][k] * w;
    a1 += ens[1][k] * w;
    a2 += ens[2][k] * w;
    a3 += ens[3][k] * w;
  }
  {
    float b = bn1[f];
    t2s[0][f] = fmaxf(a0 + b, 0.0f);
    t2s[1][f] = fmaxf(a1 + b, 0.0f);
    t2s[2][f] = fmaxf(a2 + b, 0.0f);
    t2s[3][f] = fmaxf(a3 + b, 0.0f);
  }
  __syncthreads();

  // GEMM4: msg = xi + t2 @ Wn2 + bn2 ; scatter-add into agg[dst]
  a0 = 0.0f; a1 = 0.0f; a2 = 0.0f; a3 = 0.0f;
  for (int k = 0; k < 128; ++k) {
    float w = wn2[k * 128 + f];
    a0 += t2s[0][k] * w;
    a1 += t2s[1][k] * w;
    a2 += t2s[2][k] * w;
    a3 += t2s[3][k] * w;
  }
  {
    float b = bn2[f];
    atomicAdd(&agg[(long long)dst[e0 + 0] * 128 + f], cat[0][f] + a0 + b);
    atomicAdd(&agg[(long long)dst[e0 + 1] * 128 + f], cat[1][f] + a1 + b);
    atomicAdd(&agg[(long long)dst[e0 + 2] * 128 + f], cat[2][f] + a2 + b);
    atomicAdd(&agg[(long long)dst[e0 + 3] * 128 + f], cat[3][f] + a3 + b);
  }
}

// node layernorm: h = LN(h + agg), agg = 0 ; one block per node
__global__ void node_ln_kernel(float* h, float* agg, const float* g, const float* b) {
  __shared__ float red[128];
  int f = threadIdx.x;
  int n = blockIdx.x;
  long long base = (long long)n * 128 + f;
  float v = h[base] + agg[base];
  red[f] = v;
  __syncthreads();
  for (int s = 64; s > 0; s >>= 1) {
    if (f < s) red[f] += red[f + s];
    __syncthreads();
  }
  float m = red[0] * (1.0f / 128.0f);
  __syncthreads();
  red[f] = v * v;
  __syncthreads();
  for (int s = 64; s > 0; s >>= 1) {
    if (f < s) red[f] += red[f + s];
    __syncthreads();
  }
  float q = red[0] * (1.0f / 128.0f);
  float var = q - m * m;
  float rs = rsqrtf(fmaxf(var, 0.0f) + 1e-5f);
  h[base] = (v - m) * rs * g[f] + b[f];
  agg[base] = 0.0f;
}

// decoder: out[n,:2] = mlp(h[n,:]) - noise[n,:2] ; f32 output
__global__ void decoder_kernel(const float* h, const float* w1, const float* b1,
                               const float* w2, const float* b2,
                               const float* noise, float* out) {
  __shared__ float t1s[128];
  int f = threadIdx.x;
  int n = blockIdx.x;
  float a = b1[f];
  for (int k = 0; k < 128; ++k) a += h[(long long)n * 128 + k] * w1[k * 128 + f];
  t1s[f] = fmaxf(a, 0.0f);
  __syncthreads();
  if (f < 2) {
    float s = b2[f];
    for (int k = 0; k < 128; ++k) s += t1s[k] * w2[k * 2 + f];
    s -= noise[n * 16 + f];
    out[n * 2 + f] = s;
  }
}

extern "C" void kernel_launch(void* const* d_in, const int* in_sizes, int n_in,
                              void* d_out, int out_size, void* d_ws, size_t ws_size,
                              hipStream_t stream) {
  (void)in_sizes; (void)n_in;

  const float* x      = (const float*)d_in[0];
  const float* eattr  = (const float*)d_in[1];
  const int*   eidx   = (const int*)d_in[2];
  const float* nnoise = (const float*)d_in[3];
  const float* enoise = (const float*)d_in[4];
  const float* ne_w1 = (const float*)d_in[5];  const float* ne_b1 = (const float*)d_in[6];
  const float* ne_w2 = (const float*)d_in[7];  const float* ne_b2 = (const float*)d_in[8];
  const float* ee_w1 = (const float*)d_in[9];  const float* ee_b1 = (const float*)d_in[10];
  const float* ee_w2 = (const float*)d_in[11]; const float* ee_b2 = (const float*)d_in[12];
  const float* ge_w1 = (const float*)d_in[13]; const float* ge_b1 = (const float*)d_in[14];
  const float* ge_w2 = (const float*)d_in[15]; const float* ge_b2 = (const float*)d_in[16];
  const float* gn_w1 = (const float*)d_in[17]; const float* gn_b1 = (const float*)d_in[18];
  const float* gn_w2 = (const float*)d_in[19]; const float* gn_b2 = (const float*)d_in[20];
  const float* xlng = (const float*)d_in[21]; const float* xlnb = (const float*)d_in[22];
  const float* elng = (const float*)d_in[23]; const float* elnb = (const float*)d_in[24];
  const float* d_w1 = (const float*)d_in[25]; const float* d_b1 = (const float*)d_in[26];
  const float* d_w2 = (const float*)d_in[27]; const float* d_b2 = (const float*)d_in[28];

  float* out = (float*)d_out;

  // workspace layout (fits 256 MB: idx 5.12 + h 10.24 + agg 10.24 + e(bf16) 163.84)
  char* base = (char*)d_ws;
  size_t off = 0;
  int* idx = (int*)(base + off);     off += (size_t)2 * NE * 4;
  int* flag = (int*)(base + off);    off += 16;
  float* h = (float*)(base + off);   off += (size_t)NN * 128 * 4;
  float* agg = (float*)(base + off); off += (size_t)NN * 128 * 4;
  u16* e = (u16*)(base + off);       off += (size_t)NE * 128 * 2;

  hipStreamCaptureStatus cs = hipStreamCaptureStatusNone;
  hipStreamIsCapturing(stream, &cs);
  const bool dbg = (cs == hipStreamCaptureStatusNone);

  init_kernel<<<(NN * 128 + 255) / 256, 256, 0, stream>>>(agg, NN * 128);
  idx_detect_kernel<<<1, 64, 0, stream>>>(eidx, flag);
  idx_prep_kernel<<<(2 * NE + 255) / 256, 256, 0, stream>>>(eidx, flag, idx);
  const int* src = idx;       // edge_index[0] -> x_j
  const int* dst = idx + NE;  // edge_index[1] -> x_i / aggregation target

  node_enc_kernel<<<NN, 128, 0, stream>>>(x, nnoise, ne_w1, ne_b1, ne_w2, ne_b2, h);
  edge_enc_kernel<<<NE, 128, 0, stream>>>(eattr, enoise, ee_w1, ee_b1, ee_w2, ee_b2, e);

  for (int l = 0; l < NL; ++l) {
    gnn_edge_kernel<<<NE / 4, 128, 0, stream>>>(h, e, src, dst,
        ge_w1, ge_b1, ge_w2, ge_b2, gn_w1, gn_b1, gn_w2, gn_b2,
        elng + l * 128, elnb + l * 128, agg);
    node_ln_kernel<<<NN, 128, 0, stream>>>(h, agg, xlng + l * 128, xlnb + l * 128);
  }

  decoder_kernel<<<NN, 128, 0, stream>>>(h, d_w1, d_b1, d_w2, d_b2, nnoise, out);

  if (dbg) {
    hipStreamSynchronize(stream);
    float t[6] = {0, 0, 0, 0, 0, 0};
    hipMemcpy(t, h, 16, hipMemcpyDeviceToHost);
    hipMemcpy(t + 4, out, 8, hipMemcpyDeviceToHost);
    fprintf(stderr, "KL r20 f32-fix: h[0..3]=%.5g %.5g %.5g %.5g out[0..1]=%.5g %.5g lasterr=%d\n",
            t[0], t[1], t[2], t[3], t[4], t[5], (int)hipGetLastError());
    fflush(stderr);
  }
}

// Round 21
// 23621.500 us; speedup vs baseline: 1.4913x; 1.4913x over previous
//
#include <hip/hip_runtime.h>
#include <stdio.h>

#define NN 20000
#define NE 640000
#define NL 10

typedef unsigned short u16;
typedef unsigned int u32;
typedef __attribute__((ext_vector_type(8))) __bf16 bf16x8;
typedef __attribute__((ext_vector_type(8))) unsigned short us8;
typedef __attribute__((ext_vector_type(4))) float f32x4;

__device__ __forceinline__ bf16x8 ldbf(const u16* p) {
  union { us8 u; bf16x8 b; } v;
  v.u = *(const us8*)p;
  return v.b;
}
__device__ __forceinline__ f32x4 zero4() {
  f32x4 z; z[0] = 0.f; z[1] = 0.f; z[2] = 0.f; z[3] = 0.f; return z;
}
__device__ __forceinline__ float bf2f(u16 u) {
  u32 x = ((u32)u) << 16;
  return __uint_as_float(x);
}
__device__ __forceinline__ u16 f2bf(float f) {
  u32 x = __float_as_uint(f);
  u32 r = (x + 0x7fffu + ((x >> 16) & 1u)) >> 16;
  return (u16)r;
}
// swizzled LDS element index for a [64][128] bf16 tile; 16B-chunk XOR swizzle
__device__ __forceinline__ int lad(int row, int col) {
  return (row << 7) + ((((col >> 3) ^ (row & 15)) << 3) | (col & 7));
}
__device__ __forceinline__ uint2 pack4bf(const float f[4]) {
  uint2 u;
  u.x = (u32)f2bf(f[0]) | ((u32)f2bf(f[1]) << 16);
  u.y = (u32)f2bf(f[2]) | ((u32)f2bf(f[3]) << 16);
  return u;
}
__device__ __forceinline__ void unpack4bf(uint2 u, float f[4]) {
  f[0] = bf2f((u16)(u.x & 0xffffu)); f[1] = bf2f((u16)(u.x >> 16));
  f[2] = bf2f((u16)(u.y & 0xffffu)); f[3] = bf2f((u16)(u.y >> 16));
}

// stub-named kernel retained (inert).
__global__ void LearnedSimModel_28716151341396_kernel() {}

__global__ void init_kernel(float* agg, int agg_n) {
  int i = blockIdx.x * 256 + threadIdx.x;
  if (i < agg_n) agg[i] = 0.0f;
}

__global__ void idx_detect_kernel(const int* raw, int* flag) {
  if (threadIdx.x == 0 && blockIdx.x == 0) {
    int any = 0;
    for (int k = 0; k < 16; ++k) any = any | raw[2 * k + 1];
    flag[0] = (any != 0) ? 1 : 0;  // 1 -> int32 storage
  }
}

__global__ void idx_prep_kernel(const int* raw, const int* flag, int* idx) {
  int i = blockIdx.x * 256 + threadIdx.x;
  if (i < 2 * NE) {
    int v;
    if (flag[0] != 0) v = raw[i];
    else v = (int)(((const long long*)raw)[i]);
    if (v < 0) v = 0;
    if (v >= NN) v = NN - 1;
    idx[i] = v;
  }
}

// W [K][128] f32 row-major -> Wt [128][K] bf16 (feature-major, k contiguous)
__global__ void transpose_kernel(const float* __restrict__ W, u16* __restrict__ Wt, int K) {
  int i = blockIdx.x * 256 + threadIdx.x;
  if (i < K * 128) {
    int k = i >> 7, f = i & 127;
    Wt[f * K + k] = f2bf(W[i]);
  }
}

// node encoder: h f32 + h16 bf16
__global__ void node_enc_kernel(const float* x, const float* noise,
                                const float* w1, const float* b1,
                                const float* w2, const float* b2,
                                float* h, u16* h16) {
  __shared__ float in16[16];
  __shared__ float t1s[128];
  int f = threadIdx.x;
  int n = blockIdx.x;
  if (f < 16) in16[f] = x[n * 16 + f] + noise[n * 16 + f];
  __syncthreads();
  float a = b1[f];
  for (int k = 0; k < 16; ++k) a += in16[k] * w1[k * 128 + f];
  t1s[f] = fmaxf(a, 0.0f);
  __syncthreads();
  float o = b2[f];
  for (int k = 0; k < 128; ++k) o += t1s[k] * w2[k * 128 + f];
  h[(long long)n * 128 + f] = o;
  h16[(long long)n * 128 + f] = f2bf(o);
}

__global__ void edge_enc_kernel(const float* attr, const float* noise,
                                const float* w1, const float* b1,
                                const float* w2, const float* b2,
                                u16* e) {
  __shared__ float in8[8];
  __shared__ float t1s[128];
  int f = threadIdx.x;
  int n = blockIdx.x;
  if (f < 8) in8[f] = attr[n * 8 + f] + noise[n * 8 + f];
  __syncthreads();
  float a = b1[f];
  for (int k = 0; k < 8; ++k) a += in8[k] * w1[k * 128 + f];
  t1s[f] = fmaxf(a, 0.0f);
  __syncthreads();
  float o = b2[f];
  for (int k = 0; k < 128; ++k) o += t1s[k] * w2[k * 128 + f];
  e[(long long)n * 128 + f] = f2bf(o);
}

// per-wave GEMM over a [64][128] swizzled LDS tile; A = Wt (stride K=128)
__device__ __forceinline__ void gemm128(const u16* lds, const u16* Wt,
                                        int l16, int quad, int fb, f32x4 acc[2][4]) {
  for (int ks = 0; ks < 4; ++ks) {
    int kg = ks * 32 + quad * 8;
    bf16x8 b0 = ldbf(lds + lad(0 * 16 + l16, kg));
    bf16x8 b1 = ldbf(lds + lad(1 * 16 + l16, kg));
    bf16x8 b2 = ldbf(lds + lad(2 * 16 + l16, kg));
    bf16x8 b3 = ldbf(lds + lad(3 * 16 + l16, kg));
    for (int tt = 0; tt < 2; ++tt) {
      bf16x8 a = ldbf(Wt + (size_t)(fb + tt * 16 + l16) * 128 + kg);
      acc[tt][0] = __builtin_amdgcn_mfma_f32_16x16x32_bf16(a, b0, acc[tt][0], 0, 0, 0);
      acc[tt][1] = __builtin_amdgcn_mfma_f32_16x16x32_bf16(a, b1, acc[tt][1], 0, 0, 0);
      acc[tt][2] = __builtin_amdgcn_mfma_f32_16x16x32_bf16(a, b2, acc[tt][2], 0, 0, 0);
      acc[tt][3] = __builtin_amdgcn_mfma_f32_16x16x32_bf16(a, b3, acc[tt][3], 0, 0, 0);
    }
  }
}

// ---------------- fused GNN edge kernel, MFMA, 64 edges/block ----------------
// acc[tt][et][r]: edge = et*16 + (lane&15), feature = fb + tt*16 + (lane>>4)*4 + r
__global__ __launch_bounds__(256) void gnn_edge_mfma(
    const float* __restrict__ h, const u16* __restrict__ h16, u16* __restrict__ e,
    const int* __restrict__ src, const int* __restrict__ dst,
    const u16* __restrict__ Wt_e1, const float* __restrict__ be1,
    const u16* __restrict__ Wt_e2, const float* __restrict__ be2,
    const u16* __restrict__ Wt_n1, const float* __restrict__ bn1,
    const u16* __restrict__ Wt_n2, const float* __restrict__ bn2,
    const float* __restrict__ lng, const float* __restrict__ lnb,
    float* __restrict__ agg)
{
  __shared__ __align__(16) u16 sA[64 * 128];   // xi
  __shared__ __align__(16) u16 sB[64 * 128];   // xj -> t1 -> t2
  __shared__ __align__(16) u16 sC[64 * 128];   // e  -> e_new
  __shared__ float part_s[4][64];
  __shared__ float part_q[4][64];

  const int t = threadIdx.x;
  const int e0 = blockIdx.x * 64;
  const int lane = t & 63;
  const int wave = t >> 6;
  const int l16 = lane & 15;
  const int quad = lane >> 4;
  const int fb = wave * 32;

  // stage xi = h16[dst], xj = h16[src], e rows into swizzled LDS
  for (int it = 0; it < 4; ++it) {
    int c = t + it * 256;
    int row = c >> 4, seg = c & 15;
    int di = dst[e0 + row];
    int si = src[e0 + row];
    us8 vi = *(const us8*)(h16 + (size_t)di * 128 + seg * 8);
    us8 vj = *(const us8*)(h16 + (size_t)si * 128 + seg * 8);
    us8 ve = *(const us8*)(e + (size_t)(e0 + row) * 128 + seg * 8);
    int b = (row << 7) + ((seg ^ (row & 15)) << 3);
    *(us8*)(sA + b) = vi;
    *(us8*)(sB + b) = vj;
    *(us8*)(sC + b) = ve;
  }
  __syncthreads();

  // GEMM1: t1 = relu([xi|xj|e] @ We1 + be1), K = 384
  f32x4 acc[2][4];
  for (int tt = 0; tt < 2; ++tt)
    for (int et = 0; et < 4; ++et) acc[tt][et] = zero4();
  for (int ks = 0; ks < 12; ++ks) {
    const u16* sp = (ks < 4) ? sA : ((ks < 8) ? sB : sC);
    int kg = ks * 32 + quad * 8;
    int kk = kg & 127;
    bf16x8 b0 = ldbf(sp + lad(0 * 16 + l16, kk));
    bf16x8 b1 = ldbf(sp + lad(1 * 16 + l16, kk));
    bf16x8 b2 = ldbf(sp + lad(2 * 16 + l16, kk));
    bf16x8 b3 = ldbf(sp + lad(3 * 16 + l16, kk));
    for (int tt = 0; tt < 2; ++tt) {
      bf16x8 a = ldbf(Wt_e1 + (size_t)(fb + tt * 16 + l16) * 384 + kg);
      acc[tt][0] = __builtin_amdgcn_mfma_f32_16x16x32_bf16(a, b0, acc[tt][0], 0, 0, 0);
      acc[tt][1] = __builtin_amdgcn_mfma_f32_16x16x32_bf16(a, b1, acc[tt][1], 0, 0, 0);
      acc[tt][2] = __builtin_amdgcn_mfma_f32_16x16x32_bf16(a, b2, acc[tt][2], 0, 0, 0);
      acc[tt][3] = __builtin_amdgcn_mfma_f32_16x16x32_bf16(a, b3, acc[tt][3], 0, 0, 0);
    }
  }
  __syncthreads();   // all waves done reading sB/sC in GEMM1

  // epilogue1: t1 -> sB
  for (int tt = 0; tt < 2; ++tt) {
    int f0 = fb + tt * 16 + quad * 4;
    float4 bb = *(const float4*)(be1 + f0);
    float bbv[4] = {bb.x, bb.y, bb.z, bb.w};
    for (int et = 0; et < 4; ++et) {
      int row = et * 16 + l16;
      float o[4];
      for (int r = 0; r < 4; ++r) o[r] = fmaxf(acc[tt][et][r] + bbv[r], 0.f);
      *(uint2*)(sB + lad(row, f0)) = pack4bf(o);
    }
  }
  __syncthreads();

  // GEMM2: e_new = e + t1 @ We2 + be2 ; sC := e_new ; lnv = e+e_new in regs
  for (int tt = 0; tt < 2; ++tt)
    for (int et = 0; et < 4; ++et) acc[tt][et] = zero4();
  gemm128(sB, Wt_e2, l16, quad, fb, acc);
  float lnv[2][4][4];
  for (int tt = 0; tt < 2; ++tt) {
    int f0 = fb + tt * 16 + quad * 4;
    float4 bb = *(const float4*)(be2 + f0);
    float bbv[4] = {bb.x, bb.y, bb.z, bb.w};
    for (int et = 0; et < 4; ++et) {
      int row = et * 16 + l16;
      float eo[4];
      unpack4bf(*(const uint2*)(sC + lad(row, f0)), eo);
      float en[4];
      for (int r = 0; r < 4; ++r) {
        en[r] = eo[r] + acc[tt][et][r] + bbv[r];
        lnv[tt][et][r] = eo[r] + en[r];
      }
      *(uint2*)(sC + lad(row, f0)) = pack4bf(en);
    }
  }
  // e-LN partial sums (wave-level over quads, then cross-wave via LDS)
  for (int et = 0; et < 4; ++et) {
    float s = 0.f, q = 0.f;
    for (int tt = 0; tt < 2; ++tt)
      for (int r = 0; r < 4; ++r) {
        float v = lnv[tt][et][r];
        s += v; q += v * v;
      }
    s += __shfl_xor(s, 16); s += __shfl_xor(s, 32);
    q += __shfl_xor(q, 16); q += __shfl_xor(q, 32);
    if (quad == 0) {
      part_s[wave][et * 16 + l16] = s;
      part_q[wave][et * 16 + l16] = q;
    }
  }
  __syncthreads();  // e_new + partials visible

  // e-LN apply -> global e (bf16)
  for (int et = 0; et < 4; ++et) {
    int row = et * 16 + l16;
    float s = part_s[0][row] + part_s[1][row] + part_s[2][row] + part_s[3][row];
    float q = part_q[0][row] + part_q[1][row] + part_q[2][row] + part_q[3][row];
    float m = s * (1.f / 128.f);
    float var = q * (1.f / 128.f) - m * m;
    float rs = rsqrtf(fmaxf(var, 0.f) + 1e-5f);
    for (int tt = 0; tt < 2; ++tt) {
      int f0 = fb + tt * 16 + quad * 4;
      float4 g4 = *(const float4*)(lng + f0);
      float4 b4 = *(const float4*)(lnb + f0);
      float gv[4] = {g4.x, g4.y, g4.z, g4.w};
      float bv[4] = {b4.x, b4.y, b4.z, b4.w};
      float o[4];
      for (int r = 0; r < 4; ++r)
        o[r] = (lnv[tt][et][r] - m) * rs * gv[r] + bv[r];
      *(uint2*)(e + (size_t)(e0 + row) * 128 + f0) = pack4bf(o);
    }
  }

  // GEMM3: t2 = relu([xi|e_new] @ Wn1 + bn1), K = 256
  for (int tt = 0; tt < 2; ++tt)
    for (int et = 0; et < 4; ++et) acc[tt][et] = zero4();
  for (int ks = 0; ks < 8; ++ks) {
    const u16* sp = (ks < 4) ? sA : sC;
    int kg = ks * 32 + quad * 8;
    int kk = kg & 127;
    bf16x8 b0 = ldbf(sp + lad(0 * 16 + l16, kk));
    bf16x8 b1 = ldbf(sp + lad(1 * 16 + l16, kk));
    bf16x8 b2 = ldbf(sp + lad(2 * 16 + l16, kk));
    bf16x8 b3 = ldbf(sp + lad(3 * 16 + l16, kk));
    for (int tt = 0; tt < 2; ++tt) {
      bf16x8 a = ldbf(Wt_n1 + (size_t)(fb + tt * 16 + l16) * 256 + kg);
      acc[tt][0] = __builtin_amdgcn_mfma_f32_16x16x32_bf16(a, b0, acc[tt][0], 0, 0, 0);
      acc[tt][1] = __builtin_amdgcn_mfma_f32_16x16x32_bf16(a, b1, acc[tt][1], 0, 0, 0);
      acc[tt][2] = __builtin_amdgcn_mfma_f32_16x16x32_bf16(a, b2, acc[tt][2], 0, 0, 0);
      acc[tt][3] = __builtin_amdgcn_mfma_f32_16x16x32_bf16(a, b3, acc[tt][3], 0, 0, 0);
    }
  }
  // epilogue3: t2 -> sB (sB's last readers finished before the partials barrier)
  for (int tt = 0; tt < 2; ++tt) {
    int f0 = fb + tt * 16 + quad * 4;
    float4 bb = *(const float4*)(bn1 + f0);
    float bbv[4] = {bb.x, bb.y, bb.z, bb.w};
    for (int et = 0; et < 4; ++et) {
      int row = et * 16 + l16;
      float o[4];
      for (int r = 0; r < 4; ++r) o[r] = fmaxf(acc[tt][et][r] + bbv[r], 0.f);
      *(uint2*)(sB + lad(row, f0)) = pack4bf(o);
    }
  }
  __syncthreads();

  // GEMM4: msg = xi(f32) + t2 @ Wn2 + bn2 ; atomicAdd into agg[dst]
  for (int tt = 0; tt < 2; ++tt)
    for (int et = 0; et < 4; ++et) acc[tt][et] = zero4();
  gemm128(sB, Wt_n2, l16, quad, fb, acc);
  int didx[4];
  for (int et = 0; et < 4; ++et) didx[et] = dst[e0 + et * 16 + l16];
  for (int tt = 0; tt < 2; ++tt) {
    int f0 = fb + tt * 16 + quad * 4;
    float4 bb = *(const float4*)(bn2 + f0);
    float bbv[4] = {bb.x, bb.y, bb.z, bb.w};
    for (int et = 0; et < 4; ++et) {
      float4 xi4 = *(const float4*)(h + (size_t)didx[et] * 128 + f0);
      float xv[4] = {xi4.x, xi4.y, xi4.z, xi4.w};
      float* ap = agg + (size_t)didx[et] * 128 + f0;
      for (int r = 0; r < 4; ++r)
        atomicAdd(ap + r, acc[tt][et][r] + bbv[r] + xv[r]);
    }
  }
}

// node layernorm: h = LN(h + agg) -> h f32 + h16 bf16 ; agg = 0
__global__ void node_ln_kernel(float* h, u16* h16, float* agg,
                               const float* g, const float* b) {
  __shared__ float red[128];
  int f = threadIdx.x;
  int n = blockIdx.x;
  long long base = (long long)n * 128 + f;
  float v = h[base] + agg[base];
  red[f] = v;
  __syncthreads();
  for (int s = 64; s > 0; s >>= 1) {
    if (f < s) red[f] += red[f + s];
    __syncthreads();
  }
  float m = red[0] * (1.0f / 128.0f);
  __syncthreads();
  red[f] = v * v;
  __syncthreads();
  for (int s = 64; s > 0; s >>= 1) {
    if (f < s) red[f] += red[f + s];
    __syncthreads();
  }
  float q = red[0] * (1.0f / 128.0f);
  float var = q - m * m;
  float rs = rsqrtf(fmaxf(var, 0.0f) + 1e-5f);
  float o = (v - m) * rs * g[f] + b[f];
  h[base] = o;
  h16[base] = f2bf(o);
  agg[base] = 0.0f;
}

// decoder: out[n,:2] = mlp(h) - noise[:, :2] ; f32 out
__global__ void decoder_kernel(const float* h, const float* w1, const float* b1,
                               const float* w2, const float* b2,
                               const float* noise, float* out) {
  __shared__ float t1s[128];
  int f = threadIdx.x;
  int n = blockIdx.x;
  float a = b1[f];
  for (int k = 0; k < 128; ++k) a += h[(long long)n * 128 + k] * w1[k * 128 + f];
  t1s[f] = fmaxf(a, 0.0f);
  __syncthreads();
  if (f < 2) {
    float s = b2[f];
    for (int k = 0; k < 128; ++k) s += t1s[k] * w2[k * 2 + f];
    s -= noise[n * 16 + f];
    out[n * 2 + f] = s;
  }
}

extern "C" void kernel_launch(void* const* d_in, const int* in_sizes, int n_in,
                              void* d_out, int out_size, void* d_ws, size_t ws_size,
                              hipStream_t stream) {
  (void)in_sizes; (void)n_in; (void)out_size; (void)ws_size;

  const float* x      = (const float*)d_in[0];
  const float* eattr  = (const float*)d_in[1];
  const int*   eidx   = (const int*)d_in[2];
  const float* nnoise = (const float*)d_in[3];
  const float* enoise = (const float*)d_in[4];
  const float* ne_w1 = (const float*)d_in[5];  const float* ne_b1 = (const float*)d_in[6];
  const float* ne_w2 = (const float*)d_in[7];  const float* ne_b2 = (const float*)d_in[8];
  const float* ee_w1 = (const float*)d_in[9];  const float* ee_b1 = (const float*)d_in[10];
  const float* ee_w2 = (const float*)d_in[11]; const float* ee_b2 = (const float*)d_in[12];
  const float* ge_w1 = (const float*)d_in[13]; const float* ge_b1 = (const float*)d_in[14];
  const float* ge_w2 = (const float*)d_in[15]; const float* ge_b2 = (const float*)d_in[16];
  const float* gn_w1 = (const float*)d_in[17]; const float* gn_b1 = (const float*)d_in[18];
  const float* gn_w2 = (const float*)d_in[19]; const float* gn_b2 = (const float*)d_in[20];
  const float* xlng = (const float*)d_in[21]; const float* xlnb = (const float*)d_in[22];
  const float* elng = (const float*)d_in[23]; const float* elnb = (const float*)d_in[24];
  const float* d_w1 = (const float*)d_in[25]; const float* d_b1 = (const float*)d_in[26];
  const float* d_w2 = (const float*)d_in[27]; const float* d_b2 = (const float*)d_in[28];

  float* out = (float*)d_out;

  // workspace layout (~195 MB of 256 MB)
  char* base = (char*)d_ws;
  size_t off = 0;
  int* idx = (int*)(base + off);     off += (size_t)2 * NE * 4;       // 5.12 MB
  int* flag = (int*)(base + off);    off += 16;
  float* h = (float*)(base + off);   off += (size_t)NN * 128 * 4;     // 10.24 MB
  u16* h16 = (u16*)(base + off);     off += (size_t)NN * 128 * 2;     // 5.12 MB
  float* agg = (float*)(base + off); off += (size_t)NN * 128 * 4;     // 10.24 MB
  u16* e = (u16*)(base + off);       off += (size_t)NE * 128 * 2;     // 163.84 MB
  u16* Wt_ge1 = (u16*)(base + off);  off += (size_t)384 * 128 * 2;
  u16* Wt_ge2 = (u16*)(base + off);  off += (size_t)128 * 128 * 2;
  u16* Wt_gn1 = (u16*)(base + off);  off += (size_t)256 * 128 * 2;
  u16* Wt_gn2 = (u16*)(base + off);  off += (size_t)128 * 128 * 2;

  hipStreamCaptureStatus cs = hipStreamCaptureStatusNone;
  hipStreamIsCapturing(stream, &cs);
  const bool dbg = (cs == hipStreamCaptureStatusNone);

  init_kernel<<<(NN * 128 + 255) / 256, 256, 0, stream>>>(agg, NN * 128);
  idx_detect_kernel<<<1, 64, 0, stream>>>(eidx, flag);
  idx_prep_kernel<<<(2 * NE + 255) / 256, 256, 0, stream>>>(eidx, flag, idx);
  const int* src = idx;       // edge_index[0] -> x_j
  const int* dst = idx + NE;  // edge_index[1] -> x_i / aggregation target

  transpose_kernel<<<(384 * 128 + 255) / 256, 256, 0, stream>>>(ge_w1, Wt_ge1, 384);
  transpose_kernel<<<(128 * 128 + 255) / 256, 256, 0, stream>>>(ge_w2, Wt_ge2, 128);
  transpose_kernel<<<(256 * 128 + 255) / 256, 256, 0, stream>>>(gn_w1, Wt_gn1, 256);
  transpose_kernel<<<(128 * 128 + 255) / 256, 256, 0, stream>>>(gn_w2, Wt_gn2, 128);

  node_enc_kernel<<<NN, 128, 0, stream>>>(x, nnoise, ne_w1, ne_b1, ne_w2, ne_b2, h, h16);
  edge_enc_kernel<<<NE, 128, 0, stream>>>(eattr, enoise, ee_w1, ee_b1, ee_w2, ee_b2, e);

  for (int l = 0; l < NL; ++l) {
    gnn_edge_mfma<<<NE / 64, 256, 0, stream>>>(h, h16, e, src, dst,
        Wt_ge1, ge_b1, Wt_ge2, ge_b2, Wt_gn1, gn_b1, Wt_gn2, gn_b2,
        elng + l * 128, elnb + l * 128, agg);
    node_ln_kernel<<<NN, 128, 0, stream>>>(h, h16, agg, xlng + l * 128, xlnb + l * 128);
  }

  decoder_kernel<<<NN, 128, 0, stream>>>(h, d_w1, d_b1, d_w2, d_b2, nnoise, out);

  if (dbg) {
    hipStreamSynchronize(stream);
    float t[6] = {0, 0, 0, 0, 0, 0};
    hipMemcpy(t, h, 16, hipMemcpyDeviceToHost);
    hipMemcpy(t + 4, out, 8, hipMemcpyDeviceToHost);
    fprintf(stderr, "KL r21 mfma: h[0..3]=%.5g %.5g %.5g %.5g out[0..1]=%.5g %.5g lasterr=%d\n",
            t[0], t[1], t[2], t[3], t[4], t[5], (int)hipGetLastError());
    fflush(stderr);
  }
}

// Round 22
// 5723.936 us; speedup vs baseline: 6.1542x; 4.1268x over previous
//
#include <hip/hip_runtime.h>
#include <stdio.h>

#define NN 20000
#define NE 640000
#define NL 10

typedef unsigned short u16;
typedef unsigned int u32;
typedef __attribute__((ext_vector_type(8))) __bf16 bf16x8;
typedef __attribute__((ext_vector_type(8))) unsigned short us8;
typedef __attribute__((ext_vector_type(4))) float f32x4;

__device__ __forceinline__ bf16x8 ldbf(const u16* p) {
  union { us8 u; bf16x8 b; } v;
  v.u = *(const us8*)p;
  return v.b;
}
__device__ __forceinline__ f32x4 zero4() {
  f32x4 z; z[0] = 0.f; z[1] = 0.f; z[2] = 0.f; z[3] = 0.f; return z;
}
__device__ __forceinline__ float bf2f(u16 u) {
  u32 x = ((u32)u) << 16;
  return __uint_as_float(x);
}
__device__ __forceinline__ u16 f2bf(float f) {
  u32 x = __float_as_uint(f);
  u32 r = (x + 0x7fffu + ((x >> 16) & 1u)) >> 16;
  return (u16)r;
}
// swizzled LDS element index for a [64][128] bf16 tile; 16B-chunk XOR swizzle
__device__ __forceinline__ int lad(int row, int col) {
  return (row << 7) + ((((col >> 3) ^ (row & 15)) << 3) | (col & 7));
}
__device__ __forceinline__ uint2 pack4bf(const float f[4]) {
  uint2 u;
  u.x = (u32)f2bf(f[0]) | ((u32)f2bf(f[1]) << 16);
  u.y = (u32)f2bf(f[2]) | ((u32)f2bf(f[3]) << 16);
  return u;
}
__device__ __forceinline__ void unpack4bf(uint2 u, float f[4]) {
  f[0] = bf2f((u16)(u.x & 0xffffu)); f[1] = bf2f((u16)(u.x >> 16));
  f[2] = bf2f((u16)(u.y & 0xffffu)); f[3] = bf2f((u16)(u.y >> 16));
}

// stub-named kernel retained (inert).
__global__ void LearnedSimModel_28716151341396_kernel() {}

// zero agg + dst histogram counters
__global__ void init_kernel(float* agg, int agg_n, int* cnt, int cnt_n) {
  int i = blockIdx.x * 256 + threadIdx.x;
  if (i < agg_n) agg[i] = 0.0f;
  if (i < cnt_n) cnt[i] = 0;
}

__global__ void idx_detect_kernel(const int* raw, int* flag) {
  if (threadIdx.x == 0 && blockIdx.x == 0) {
    int any = 0;
    for (int k = 0; k < 16; ++k) any = any | raw[2 * k + 1];
    flag[0] = (any != 0) ? 1 : 0;  // 1 -> int32 storage
  }
}

__global__ void idx_prep_kernel(const int* raw, const int* flag, int* idx0) {
  int i = blockIdx.x * 256 + threadIdx.x;
  if (i < 2 * NE) {
    int v;
    if (flag[0] != 0) v = raw[i];
    else v = (int)(((const long long*)raw)[i]);
    if (v < 0) v = 0;
    if (v >= NN) v = NN - 1;
    idx0[i] = v;
  }
}

__global__ void hist_kernel(const int* dst0, int* cnt) {
  int i = blockIdx.x * 256 + threadIdx.x;
  if (i < NE) atomicAdd(&cnt[dst0[i]], 1);
}

// exclusive prefix sum of cnt[NN] -> cursor[NN] (single block, 1024 threads)
__global__ void prefix_kernel(const int* cnt, int* cursor) {
  __shared__ int buf[1024];
  __shared__ int carry;
  int t = threadIdx.x;
  if (t == 0) carry = 0;
  __syncthreads();
  for (int base = 0; base < NN; base += 1024) {
    int v = (base + t < NN) ? cnt[base + t] : 0;
    buf[t] = v;
    __syncthreads();
    for (int s = 1; s < 1024; s <<= 1) {
      int add = (t >= s) ? buf[t - s] : 0;
      __syncthreads();
      buf[t] += add;
      __syncthreads();
    }
    int excl = buf[t] - v + carry;
    if (base + t < NN) cursor[base + t] = excl;
    __syncthreads();
    if (t == 0) carry = carry + buf[1023];
    __syncthreads();
  }
}

// scatter edges into dst-sorted order; perm[pos] = original edge id
__global__ void scatter_kernel(const int* src0, const int* dst0, int* cursor,
                               int* src_s, int* dst_s, int* perm) {
  int i = blockIdx.x * 256 + threadIdx.x;
  if (i < NE) {
    int d = dst0[i];
    int pos = atomicAdd(&cursor[d], 1);
    perm[pos] = i;
    src_s[pos] = src0[i];
    dst_s[pos] = d;
  }
}

// W [K][128] f32 row-major -> Wt [128][K] bf16 (feature-major, k contiguous)
__global__ void transpose_kernel(const float* __restrict__ W, u16* __restrict__ Wt, int K) {
  int i = blockIdx.x * 256 + threadIdx.x;
  if (i < K * 128) {
    int k = i >> 7, f = i & 127;
    Wt[f * K + k] = f2bf(W[i]);
  }
}

// node encoder: h f32 + h16 bf16
__global__ void node_enc_kernel(const float* x, const float* noise,
                                const float* w1, const float* b1,
                                const float* w2, const float* b2,
                                float* h, u16* h16) {
  __shared__ float in16[16];
  __shared__ float t1s[128];
  int f = threadIdx.x;
  int n = blockIdx.x;
  if (f < 16) in16[f] = x[n * 16 + f] + noise[n * 16 + f];
  __syncthreads();
  float a = b1[f];
  for (int k = 0; k < 16; ++k) a += in16[k] * w1[k * 128 + f];
  t1s[f] = fmaxf(a, 0.0f);
  __syncthreads();
  float o = b2[f];
  for (int k = 0; k < 128; ++k) o += t1s[k] * w2[k * 128 + f];
  h[(long long)n * 128 + f] = o;
  h16[(long long)n * 128 + f] = f2bf(o);
}

// edge encoder writing directly into dst-sorted e layout via perm gather
__global__ void edge_enc_kernel(const float* attr, const float* noise,
                                const int* perm,
                                const float* w1, const float* b1,
                                const float* w2, const float* b2,
                                u16* e) {
  __shared__ float in8[8];
  __shared__ float t1s[128];
  int f = threadIdx.x;
  int j = blockIdx.x;          // sorted position
  int p = perm[j];             // original edge id
  if (f < 8) in8[f] = attr[p * 8 + f] + noise[p * 8 + f];
  __syncthreads();
  float a = b1[f];
  for (int k = 0; k < 8; ++k) a += in8[k] * w1[k * 128 + f];
  t1s[f] = fmaxf(a, 0.0f);
  __syncthreads();
  float o = b2[f];
  for (int k = 0; k < 128; ++k) o += t1s[k] * w2[k * 128 + f];
  e[(long long)j * 128 + f] = f2bf(o);
}

// per-wave GEMM over a [64][128] swizzled LDS tile; A = Wt (stride K=128)
__device__ __forceinline__ void gemm128(const u16* lds, const u16* Wt,
                                        int l16, int quad, int fb, f32x4 acc[2][4]) {
  for (int ks = 0; ks < 4; ++ks) {
    int kg = ks * 32 + quad * 8;
    bf16x8 b0 = ldbf(lds + lad(0 * 16 + l16, kg));
    bf16x8 b1 = ldbf(lds + lad(1 * 16 + l16, kg));
    bf16x8 b2 = ldbf(lds + lad(2 * 16 + l16, kg));
    bf16x8 b3 = ldbf(lds + lad(3 * 16 + l16, kg));
    for (int tt = 0; tt < 2; ++tt) {
      bf16x8 a = ldbf(Wt + (size_t)(fb + tt * 16 + l16) * 128 + kg);
      acc[tt][0] = __builtin_amdgcn_mfma_f32_16x16x32_bf16(a, b0, acc[tt][0], 0, 0, 0);
      acc[tt][1] = __builtin_amdgcn_mfma_f32_16x16x32_bf16(a, b1, acc[tt][1], 0, 0, 0);
      acc[tt][2] = __builtin_amdgcn_mfma_f32_16x16x32_bf16(a, b2, acc[tt][2], 0, 0, 0);
      acc[tt][3] = __builtin_amdgcn_mfma_f32_16x16x32_bf16(a, b3, acc[tt][3], 0, 0, 0);
    }
  }
}

// ---------------- fused GNN edge kernel, MFMA, 64 sorted edges/block --------
// LDS pool: [0,48K) three 64x128 bf16 tiles; 48K..50K LN partials; 50K sDst.
// GEMM4 result overlays [0,33K) as a 64x129 f32 msg tile (tiles dead by then).
__global__ __launch_bounds__(256) void gnn_edge_mfma(
    const float* __restrict__ h, const u16* __restrict__ h16, u16* __restrict__ e,
    const int* __restrict__ src_s, const int* __restrict__ dst_s,
    const u16* __restrict__ Wt_e1, const float* __restrict__ be1,
    const u16* __restrict__ Wt_e2, const float* __restrict__ be2,
    const u16* __restrict__ Wt_n1, const float* __restrict__ bn1,
    const u16* __restrict__ Wt_n2, const float* __restrict__ bn2,
    const float* __restrict__ lng, const float* __restrict__ lnb,
    float* __restrict__ agg)
{
  __shared__ __align__(16) char smem[51456];
  u16* sA = (u16*)smem;                     // xi   (16 KB)
  u16* sB = (u16*)(smem + 16384);           // xj -> t1 -> t2
  u16* sC = (u16*)(smem + 32768);           // e  -> e_new
  float* part_s = (float*)(smem + 49152);   // [4][64]
  float* part_q = (float*)(smem + 50176);   // [4][64]... (50176..51200)
  int* sDst = (int*)(smem + 51200);         // [64]
  float* msgf = (float*)smem;               // 64x129 f32 overlay (33 KB)

  const int t = threadIdx.x;
  const int e0 = blockIdx.x * 64;
  const int lane = t & 63;
  const int wave = t >> 6;
  const int l16 = lane & 15;
  const int quad = lane >> 4;
  const int fb = wave * 32;

  if (t < 64) sDst[t] = dst_s[e0 + t];

  // stage xi = h16[dst], xj = h16[src], e rows into swizzled LDS
  for (int it = 0; it < 4; ++it) {
    int c = t + it * 256;
    int row = c >> 4, seg = c & 15;
    int di = dst_s[e0 + row];
    int si = src_s[e0 + row];
    us8 vi = *(const us8*)(h16 + (size_t)di * 128 + seg * 8);
    us8 vj = *(const us8*)(h16 + (size_t)si * 128 + seg * 8);
    us8 ve = *(const us8*)(e + (size_t)(e0 + row) * 128 + seg * 8);
    int b = (row << 7) + ((seg ^ (row & 15)) << 3);
    *(us8*)(sA + b) = vi;
    *(us8*)(sB + b) = vj;
    *(us8*)(sC + b) = ve;
  }
  __syncthreads();

  // GEMM1: t1 = relu([xi|xj|e] @ We1 + be1), K = 384
  f32x4 acc[2][4];
  for (int tt = 0; tt < 2; ++tt)
    for (int et = 0; et < 4; ++et) acc[tt][et] = zero4();
  for (int ks = 0; ks < 12; ++ks) {
    const u16* sp = (ks < 4) ? sA : ((ks < 8) ? sB : sC);
    int kg = ks * 32 + quad * 8;
    int kk = kg & 127;
    bf16x8 b0 = ldbf(sp + lad(0 * 16 + l16, kk));
    bf16x8 b1 = ldbf(sp + lad(1 * 16 + l16, kk));
    bf16x8 b2 = ldbf(sp + lad(2 * 16 + l16, kk));
    bf16x8 b3 = ldbf(sp + lad(3 * 16 + l16, kk));
    for (int tt = 0; tt < 2; ++tt) {
      bf16x8 a = ldbf(Wt_e1 + (size_t)(fb + tt * 16 + l16) * 384 + kg);
      acc[tt][0] = __builtin_amdgcn_mfma_f32_16x16x32_bf16(a, b0, acc[tt][0], 0, 0, 0);
      acc[tt][1] = __builtin_amdgcn_mfma_f32_16x16x32_bf16(a, b1, acc[tt][1], 0, 0, 0);
      acc[tt][2] = __builtin_amdgcn_mfma_f32_16x16x32_bf16(a, b2, acc[tt][2], 0, 0, 0);
      acc[tt][3] = __builtin_amdgcn_mfma_f32_16x16x32_bf16(a, b3, acc[tt][3], 0, 0, 0);
    }
  }
  __syncthreads();

  // epilogue1: t1 -> sB
  for (int tt = 0; tt < 2; ++tt) {
    int f0 = fb + tt * 16 + quad * 4;
    float4 bb = *(const float4*)(be1 + f0);
    float bbv[4] = {bb.x, bb.y, bb.z, bb.w};
    for (int et = 0; et < 4; ++et) {
      int row = et * 16 + l16;
      float o[4];
      for (int r = 0; r < 4; ++r) o[r] = fmaxf(acc[tt][et][r] + bbv[r], 0.f);
      *(uint2*)(sB + lad(row, f0)) = pack4bf(o);
    }
  }
  __syncthreads();

  // GEMM2: e_new = e + t1 @ We2 + be2 ; sC := e_new ; lnv = e+e_new in regs
  for (int tt = 0; tt < 2; ++tt)
    for (int et = 0; et < 4; ++et) acc[tt][et] = zero4();
  gemm128(sB, Wt_e2, l16, quad, fb, acc);
  float lnv[2][4][4];
  for (int tt = 0; tt < 2; ++tt) {
    int f0 = fb + tt * 16 + quad * 4;
    float4 bb = *(const float4*)(be2 + f0);
    float bbv[4] = {bb.x, bb.y, bb.z, bb.w};
    for (int et = 0; et < 4; ++et) {
      int row = et * 16 + l16;
      float eo[4];
      unpack4bf(*(const uint2*)(sC + lad(row, f0)), eo);
      float en[4];
      for (int r = 0; r < 4; ++r) {
        en[r] = eo[r] + acc[tt][et][r] + bbv[r];
        lnv[tt][et][r] = eo[r] + en[r];
      }
      *(uint2*)(sC + lad(row, f0)) = pack4bf(en);
    }
  }
  for (int et = 0; et < 4; ++et) {
    float s = 0.f, q = 0.f;
    for (int tt = 0; tt < 2; ++tt)
      for (int r = 0; r < 4; ++r) {
        float v = lnv[tt][et][r];
        s += v; q += v * v;
      }
    s += __shfl_xor(s, 16); s += __shfl_xor(s, 32);
    q += __shfl_xor(q, 16); q += __shfl_xor(q, 32);
    if (quad == 0) {
      part_s[wave * 64 + et * 16 + l16] = s;
      part_q[wave * 64 + et * 16 + l16] = q;
    }
  }
  __syncthreads();

  // e-LN apply -> global e (bf16)
  for (int et = 0; et < 4; ++et) {
    int row = et * 16 + l16;
    float s = part_s[row] + part_s[64 + row] + part_s[128 + row] + part_s[192 + row];
    float q = part_q[row] + part_q[64 + row] + part_q[128 + row] + part_q[192 + row];
    float m = s * (1.f / 128.f);
    float var = q * (1.f / 128.f) - m * m;
    float rs = rsqrtf(fmaxf(var, 0.f) + 1e-5f);
    for (int tt = 0; tt < 2; ++tt) {
      int f0 = fb + tt * 16 + quad * 4;
      float4 g4 = *(const float4*)(lng + f0);
      float4 b4 = *(const float4*)(lnb + f0);
      float gv[4] = {g4.x, g4.y, g4.z, g4.w};
      float bv[4] = {b4.x, b4.y, b4.z, b4.w};
      float o[4];
      for (int r = 0; r < 4; ++r)
        o[r] = (lnv[tt][et][r] - m) * rs * gv[r] + bv[r];
      *(uint2*)(e + (size_t)(e0 + row) * 128 + f0) = pack4bf(o);
    }
  }

  // GEMM3: t2 = relu([xi|e_new] @ Wn1 + bn1), K = 256
  for (int tt = 0; tt < 2; ++tt)
    for (int et = 0; et < 4; ++et) acc[tt][et] = zero4();
  for (int ks = 0; ks < 8; ++ks) {
    const u16* sp = (ks < 4) ? sA : sC;
    int kg = ks * 32 + quad * 8;
    int kk = kg & 127;
    bf16x8 b0 = ldbf(sp + lad(0 * 16 + l16, kk));
    bf16x8 b1 = ldbf(sp + lad(1 * 16 + l16, kk));
    bf16x8 b2 = ldbf(sp + lad(2 * 16 + l16, kk));
    bf16x8 b3 = ldbf(sp + lad(3 * 16 + l16, kk));
    for (int tt = 0; tt < 2; ++tt) {
      bf16x8 a = ldbf(Wt_n1 + (size_t)(fb + tt * 16 + l16) * 256 + kg);
      acc[tt][0] = __builtin_amdgcn_mfma_f32_16x16x32_bf16(a, b0, acc[tt][0], 0, 0, 0);
      acc[tt][1] = __builtin_amdgcn_mfma_f32_16x16x32_bf16(a, b1, acc[tt][1], 0, 0, 0);
      acc[tt][2] = __builtin_amdgcn_mfma_f32_16x16x32_bf16(a, b2, acc[tt][2], 0, 0, 0);
      acc[tt][3] = __builtin_amdgcn_mfma_f32_16x16x32_bf16(a, b3, acc[tt][3], 0, 0, 0);
    }
  }
  // epilogue3: t2 -> sB
  for (int tt = 0; tt < 2; ++tt) {
    int f0 = fb + tt * 16 + quad * 4;
    float4 bb = *(const float4*)(bn1 + f0);
    float bbv[4] = {bb.x, bb.y, bb.z, bb.w};
    for (int et = 0; et < 4; ++et) {
      int row = et * 16 + l16;
      float o[4];
      for (int r = 0; r < 4; ++r) o[r] = fmaxf(acc[tt][et][r] + bbv[r], 0.f);
      *(uint2*)(sB + lad(row, f0)) = pack4bf(o);
    }
  }
  __syncthreads();

  // GEMM4: msg = xi(f32) + t2 @ Wn2 + bn2 -> LDS msg tile, then segment-sum
  for (int tt = 0; tt < 2; ++tt)
    for (int et = 0; et < 4; ++et) acc[tt][et] = zero4();
  gemm128(sB, Wt_n2, l16, quad, fb, acc);
  __syncthreads();  // all waves done reading sB; tiles now dead -> msgf overlay
  for (int tt = 0; tt < 2; ++tt) {
    int f0 = fb + tt * 16 + quad * 4;
    float4 bb = *(const float4*)(bn2 + f0);
    float bbv[4] = {bb.x, bb.y, bb.z, bb.w};
    for (int et = 0; et < 4; ++et) {
      int row = et * 16 + l16;
      int d = sDst[row];
      float4 xi4 = *(const float4*)(h + (size_t)d * 128 + f0);
      float xv[4] = {xi4.x, xi4.y, xi4.z, xi4.w};
      float* mp = msgf + row * 129 + f0;
      for (int r = 0; r < 4; ++r) mp[r] = acc[tt][et][r] + bbv[r] + xv[r];
    }
  }
  __syncthreads();

  // segment reduction over sorted dst: ~2-4 atomic rows per block
  if (t < 128) {
    int f = t;
    float a = 0.f;
    for (int j = 0; j < 64; ++j) {
      a += msgf[j * 129 + f];
      int dj = sDst[j];
      if (j == 63 || sDst[j + 1] != dj) {
        atomicAdd(&agg[(size_t)dj * 128 + f], a);
        a = 0.f;
      }
    }
  }
}

// node layernorm: h = LN(h + agg) -> h f32 + h16 bf16 ; agg = 0
__global__ void node_ln_kernel(float* h, u16* h16, float* agg,
                               const float* g, const float* b) {
  __shared__ float red[128];
  int f = threadIdx.x;
  int n = blockIdx.x;
  long long base = (long long)n * 128 + f;
  float v = h[base] + agg[base];
  red[f] = v;
  __syncthreads();
  for (int s = 64; s > 0; s >>= 1) {
    if (f < s) red[f] += red[f + s];
    __syncthreads();
  }
  float m = red[0] * (1.0f / 128.0f);
  __syncthreads();
  red[f] = v * v;
  __syncthreads();
  for (int s = 64; s > 0; s >>= 1) {
    if (f < s) red[f] += red[f + s];
    __syncthreads();
  }
  float q = red[0] * (1.0f / 128.0f);
  float var = q - m * m;
  float rs = rsqrtf(fmaxf(var, 0.0f) + 1e-5f);
  float o = (v - m) * rs * g[f] + b[f];
  h[base] = o;
  h16[base] = f2bf(o);
  agg[base] = 0.0f;
}

// decoder: out[n,:2] = mlp(h) - noise[:, :2] ; f32 out
__global__ void decoder_kernel(const float* h, const float* w1, const float* b1,
                               const float* w2, const float* b2,
                               const float* noise, float* out) {
  __shared__ float t1s[128];
  int f = threadIdx.x;
  int n = blockIdx.x;
  float a = b1[f];
  for (int k = 0; k < 128; ++k) a += h[(long long)n * 128 + k] * w1[k * 128 + f];
  t1s[f] = fmaxf(a, 0.0f);
  __syncthreads();
  if (f < 2) {
    float s = b2[f];
    for (int k = 0; k < 128; ++k) s += t1s[k] * w2[k * 2 + f];
    s -= noise[n * 16 + f];
    out[n * 2 + f] = s;
  }
}

extern "C" void kernel_launch(void* const* d_in, const int* in_sizes, int n_in,
                              void* d_out, int out_size, void* d_ws, size_t ws_size,
                              hipStream_t stream) {
  (void)in_sizes; (void)n_in; (void)out_size; (void)ws_size;

  const float* x      = (const float*)d_in[0];
  const float* eattr  = (const float*)d_in[1];
  const int*   eidx   = (const int*)d_in[2];
  const float* nnoise = (const float*)d_in[3];
  const float* enoise = (const float*)d_in[4];
  const float* ne_w1 = (const float*)d_in[5];  const float* ne_b1 = (const float*)d_in[6];
  const float* ne_w2 = (const float*)d_in[7];  const float* ne_b2 = (const float*)d_in[8];
  const float* ee_w1 = (const float*)d_in[9];  const float* ee_b1 = (const float*)d_in[10];
  const float* ee_w2 = (const float*)d_in[11]; const float* ee_b2 = (const float*)d_in[12];
  const float* ge_w1 = (const float*)d_in[13]; const float* ge_b1 = (const float*)d_in[14];
  const float* ge_w2 = (const float*)d_in[15]; const float* ge_b2 = (const float*)d_in[16];
  const float* gn_w1 = (const float*)d_in[17]; const float* gn_b1 = (const float*)d_in[18];
  const float* gn_w2 = (const float*)d_in[19]; const float* gn_b2 = (const float*)d_in[20];
  const float* xlng = (const float*)d_in[21]; const float* xlnb = (const float*)d_in[22];
  const float* elng = (const float*)d_in[23]; const float* elnb = (const float*)d_in[24];
  const float* d_w1 = (const float*)d_in[25]; const float* d_b1 = (const float*)d_in[26];
  const float* d_w2 = (const float*)d_in[27]; const float* d_b2 = (const float*)d_in[28];

  float* out = (float*)d_out;

  // workspace layout (~203 MB of 256 MB)
  char* base = (char*)d_ws;
  size_t off = 0;
  int* idx0 = (int*)(base + off);    off += (size_t)2 * NE * 4;       // unsorted src/dst
  int* src_s = (int*)(base + off);   off += (size_t)NE * 4;
  int* dst_s = (int*)(base + off);   off += (size_t)NE * 4;
  int* perm = (int*)(base + off);    off += (size_t)NE * 4;
  int* cnt = (int*)(base + off);     off += (size_t)NN * 4;
  int* cursor = (int*)(base + off);  off += (size_t)NN * 4;
  int* flag = (int*)(base + off);    off += 16;
  float* h = (float*)(base + off);   off += (size_t)NN * 128 * 4;
  u16* h16 = (u16*)(base + off);     off += (size_t)NN * 128 * 2;
  float* agg = (float*)(base + off); off += (size_t)NN * 128 * 4;
  u16* e = (u16*)(base + off);       off += (size_t)NE * 128 * 2;
  u16* Wt_ge1 = (u16*)(base + off);  off += (size_t)384 * 128 * 2;
  u16* Wt_ge2 = (u16*)(base + off);  off += (size_t)128 * 128 * 2;
  u16* Wt_gn1 = (u16*)(base + off);  off += (size_t)256 * 128 * 2;
  u16* Wt_gn2 = (u16*)(base + off);  off += (size_t)128 * 128 * 2;

  hipStreamCaptureStatus cs = hipStreamCaptureStatusNone;
  hipStreamIsCapturing(stream, &cs);
  const bool dbg = (cs == hipStreamCaptureStatusNone);

  const int* src0 = idx0;
  const int* dst0 = idx0 + NE;

  init_kernel<<<(NN * 128 + 255) / 256, 256, 0, stream>>>(agg, NN * 128, cnt, NN);
  idx_detect_kernel<<<1, 64, 0, stream>>>(eidx, flag);
  idx_prep_kernel<<<(2 * NE + 255) / 256, 256, 0, stream>>>(eidx, flag, idx0);

  // counting sort by dst (once per call; reused by all 10 layers)
  hist_kernel<<<(NE + 255) / 256, 256, 0, stream>>>(dst0, cnt);
  prefix_kernel<<<1, 1024, 0, stream>>>(cnt, cursor);
  scatter_kernel<<<(NE + 255) / 256, 256, 0, stream>>>(src0, dst0, cursor,
                                                       src_s, dst_s, perm);

  transpose_kernel<<<(384 * 128 + 255) / 256, 256, 0, stream>>>(ge_w1, Wt_ge1, 384);
  transpose_kernel<<<(128 * 128 + 255) / 256, 256, 0, stream>>>(ge_w2, Wt_ge2, 128);
  transpose_kernel<<<(256 * 128 + 255) / 256, 256, 0, stream>>>(gn_w1, Wt_gn1, 256);
  transpose_kernel<<<(128 * 128 + 255) / 256, 256, 0, stream>>>(gn_w2, Wt_gn2, 128);

  node_enc_kernel<<<NN, 128, 0, stream>>>(x, nnoise, ne_w1, ne_b1, ne_w2, ne_b2, h, h16);
  edge_enc_kernel<<<NE, 128, 0, stream>>>(eattr, enoise, perm,
                                          ee_w1, ee_b1, ee_w2, ee_b2, e);

  for (int l = 0; l < NL; ++l) {
    gnn_edge_mfma<<<NE / 64, 256, 0, stream>>>(h, h16, e, src_s, dst_s,
        Wt_ge1, ge_b1, Wt_ge2, ge_b2, Wt_gn1, gn_b1, Wt_gn2, gn_b2,
        elng + l * 128, elnb + l * 128, agg);
    node_ln_kernel<<<NN, 128, 0, stream>>>(h, h16, agg, xlng + l * 128, xlnb + l * 128);
  }

  decoder_kernel<<<NN, 128, 0, stream>>>(h, d_w1, d_b1, d_w2, d_b2, nnoise, out);

  if (dbg) {
    hipStreamSynchronize(stream);
    float tbuf[6] = {0, 0, 0, 0, 0, 0};
    hipMemcpy(tbuf, h, 16, hipMemcpyDeviceToHost);
    hipMemcpy(tbuf + 4, out, 8, hipMemcpyDeviceToHost);
    fprintf(stderr, "KL r22 sorted: h[0..3]=%.5g %.5g %.5g %.5g out[0..1]=%.5g %.5g lasterr=%d\n",
            tbuf[0], tbuf[1], tbuf[2], tbuf[3], tbuf[4], tbuf[5], (int)hipGetLastError());
    fflush(stderr);
  }
}

// Round 23
// 4603.277 us; speedup vs baseline: 7.6525x; 1.2434x over previous
//
#include <hip/hip_runtime.h>
#include <stdio.h>

#define NN 20000
#define NE 640000
#define NL 10

typedef unsigned short u16;
typedef unsigned int u32;
typedef __attribute__((ext_vector_type(8))) __bf16 bf16x8;
typedef __attribute__((ext_vector_type(8))) unsigned short us8;
typedef __attribute__((ext_vector_type(4))) float f32x4;

__device__ __forceinline__ bf16x8 ldbf(const u16* p) {
  union { us8 u; bf16x8 b; } v;
  v.u = *(const us8*)p;
  return v.b;
}
__device__ __forceinline__ f32x4 zero4() {
  f32x4 z; z[0] = 0.f; z[1] = 0.f; z[2] = 0.f; z[3] = 0.f; return z;
}
__device__ __forceinline__ float bf2f(u16 u) {
  u32 x = ((u32)u) << 16;
  return __uint_as_float(x);
}
__device__ __forceinline__ u16 f2bf(float f) {
  u32 x = __float_as_uint(f);
  u32 r = (x + 0x7fffu + ((x >> 16) & 1u)) >> 16;
  return (u16)r;
}
// swizzled LDS element index for a [64][128] bf16 tile; 16B-chunk XOR swizzle
__device__ __forceinline__ int lad(int row, int col) {
  return (row << 7) + ((((col >> 3) ^ (row & 15)) << 3) | (col & 7));
}
__device__ __forceinline__ uint2 pack4bf(const float f[4]) {
  uint2 u;
  u.x = (u32)f2bf(f[0]) | ((u32)f2bf(f[1]) << 16);
  u.y = (u32)f2bf(f[2]) | ((u32)f2bf(f[3]) << 16);
  return u;
}
__device__ __forceinline__ void unpack4bf(uint2 u, float f[4]) {
  f[0] = bf2f((u16)(u.x & 0xffffu)); f[1] = bf2f((u16)(u.x >> 16));
  f[2] = bf2f((u16)(u.y & 0xffffu)); f[3] = bf2f((u16)(u.y >> 16));
}

// stub-named kernel retained (inert).
__global__ void LearnedSimModel_28716151341396_kernel() {}

// zero agg + dst histogram counters
__global__ void init_kernel(float* agg, int agg_n, int* cnt, int cnt_n) {
  int i = blockIdx.x * 256 + threadIdx.x;
  if (i < agg_n) agg[i] = 0.0f;
  if (i < cnt_n) cnt[i] = 0;
}

__global__ void idx_detect_kernel(const int* raw, int* flag) {
  if (threadIdx.x == 0 && blockIdx.x == 0) {
    int any = 0;
    for (int k = 0; k < 16; ++k) any = any | raw[2 * k + 1];
    flag[0] = (any != 0) ? 1 : 0;  // 1 -> int32 storage
  }
}

__global__ void idx_prep_kernel(const int* raw, const int* flag, int* idx0) {
  int i = blockIdx.x * 256 + threadIdx.x;
  if (i < 2 * NE) {
    int v;
    if (flag[0] != 0) v = raw[i];
    else v = (int)(((const long long*)raw)[i]);
    if (v < 0) v = 0;
    if (v >= NN) v = NN - 1;
    idx0[i] = v;
  }
}

__global__ void hist_kernel(const int* dst0, int* cnt) {
  int i = blockIdx.x * 256 + threadIdx.x;
  if (i < NE) atomicAdd(&cnt[dst0[i]], 1);
}

// exclusive prefix sum of cnt[NN] -> cursor[NN] (single block, 1024 threads)
__global__ void prefix_kernel(const int* cnt, int* cursor) {
  __shared__ int buf[1024];
  __shared__ int carry;
  int t = threadIdx.x;
  if (t == 0) carry = 0;
  __syncthreads();
  for (int base = 0; base < NN; base += 1024) {
    int v = (base + t < NN) ? cnt[base + t] : 0;
    buf[t] = v;
    __syncthreads();
    for (int s = 1; s < 1024; s <<= 1) {
      int add = (t >= s) ? buf[t - s] : 0;
      __syncthreads();
      buf[t] += add;
      __syncthreads();
    }
    int excl = buf[t] - v + carry;
    if (base + t < NN) cursor[base + t] = excl;
    __syncthreads();
    if (t == 0) carry = carry + buf[1023];
    __syncthreads();
  }
}

// scatter edges into dst-sorted order; perm[pos] = original edge id
__global__ void scatter_kernel(const int* src0, const int* dst0, int* cursor,
                               int* src_s, int* dst_s, int* perm) {
  int i = blockIdx.x * 256 + threadIdx.x;
  if (i < NE) {
    int d = dst0[i];
    int pos = atomicAdd(&cursor[d], 1);
    perm[pos] = i;
    src_s[pos] = src0[i];
    dst_s[pos] = d;
  }
}

// W [K][128] f32 row-major -> Wt [128][K] bf16 (feature-major, k contiguous)
__global__ void transpose_kernel(const float* __restrict__ W, u16* __restrict__ Wt, int K) {
  int i = blockIdx.x * 256 + threadIdx.x;
  if (i < K * 128) {
    int k = i >> 7, f = i & 127;
    Wt[f * K + k] = f2bf(W[i]);
  }
}

// node encoder: h f32 + h16 bf16
__global__ void node_enc_kernel(const float* x, const float* noise,
                                const float* w1, const float* b1,
                                const float* w2, const float* b2,
                                float* h, u16* h16) {
  __shared__ float in16[16];
  __shared__ float t1s[128];
  int f = threadIdx.x;
  int n = blockIdx.x;
  if (f < 16) in16[f] = x[n * 16 + f] + noise[n * 16 + f];
  __syncthreads();
  float a = b1[f];
  for (int k = 0; k < 16; ++k) a += in16[k] * w1[k * 128 + f];
  t1s[f] = fmaxf(a, 0.0f);
  __syncthreads();
  float o = b2[f];
  for (int k = 0; k < 128; ++k) o += t1s[k] * w2[k * 128 + f];
  h[(long long)n * 128 + f] = o;
  h16[(long long)n * 128 + f] = f2bf(o);
}

// per-wave GEMM over a [64][128] swizzled LDS tile; A = Wt (stride K=128)
__device__ __forceinline__ void gemm128(const u16* lds, const u16* Wt,
                                        int l16, int quad, int fb, f32x4 acc[2][4]) {
  for (int ks = 0; ks < 4; ++ks) {
    int kg = ks * 32 + quad * 8;
    bf16x8 b0 = ldbf(lds + lad(0 * 16 + l16, kg));
    bf16x8 b1 = ldbf(lds + lad(1 * 16 + l16, kg));
    bf16x8 b2 = ldbf(lds + lad(2 * 16 + l16, kg));
    bf16x8 b3 = ldbf(lds + lad(3 * 16 + l16, kg));
    for (int tt = 0; tt < 2; ++tt) {
      bf16x8 a = ldbf(Wt + (size_t)(fb + tt * 16 + l16) * 128 + kg);
      acc[tt][0] = __builtin_amdgcn_mfma_f32_16x16x32_bf16(a, b0, acc[tt][0], 0, 0, 0);
      acc[tt][1] = __builtin_amdgcn_mfma_f32_16x16x32_bf16(a, b1, acc[tt][1], 0, 0, 0);
      acc[tt][2] = __builtin_amdgcn_mfma_f32_16x16x32_bf16(a, b2, acc[tt][2], 0, 0, 0);
      acc[tt][3] = __builtin_amdgcn_mfma_f32_16x16x32_bf16(a, b3, acc[tt][3], 0, 0, 0);
    }
  }
}

// ---------------- MFMA edge encoder: 64 sorted edges/block, 256 threads -----
// stage1 (K=8) scalar -> LDS tile; stage2 (128x128) via gemm128
__global__ __launch_bounds__(256) void edge_enc_mfma(
    const float* __restrict__ attr, const float* __restrict__ noise,
    const int* __restrict__ perm,
    const float* __restrict__ w1, const float* __restrict__ b1,
    const u16* __restrict__ Wt2, const float* __restrict__ b2,
    u16* __restrict__ e)
{
  __shared__ __align__(16) u16 sT[64 * 128];
  __shared__ float sIn[64][8];
  __shared__ int sPerm[64];

  const int t = threadIdx.x;
  const int e0 = blockIdx.x * 64;
  if (t < 64) sPerm[t] = perm[e0 + t];
  __syncthreads();

  // load attr+noise: 512 floats, 2 per thread
  for (int it = 0; it < 2; ++it) {
    int c = t + it * 256;
    int row = c >> 3, k = c & 7;
    int p = sPerm[row];
    sIn[row][k] = attr[(size_t)p * 8 + k] + noise[(size_t)p * 8 + k];
  }
  __syncthreads();

  // stage1: t1 = relu(in8 @ w1 + b1) -> swizzled bf16 tile
  {
    int f = t & 127;
    int r0 = (t >> 7) * 32;
    float wc[8];
    for (int k = 0; k < 8; ++k) wc[k] = w1[k * 128 + f];
    float bb = b1[f];
    for (int j = 0; j < 32; ++j) {
      int row = r0 + j;
      float a = bb;
      for (int k = 0; k < 8; ++k) a += sIn[row][k] * wc[k];
      sT[lad(row, f)] = f2bf(fmaxf(a, 0.f));
    }
  }
  __syncthreads();

  // stage2: e = t1 @ W2 + b2 (no relu), MFMA
  const int lane = t & 63;
  const int wave = t >> 6;
  const int l16 = lane & 15;
  const int quad = lane >> 4;
  const int fb = wave * 32;
  f32x4 acc[2][4];
  for (int tt = 0; tt < 2; ++tt)
    for (int et = 0; et < 4; ++et) acc[tt][et] = zero4();
  gemm128(sT, Wt2, l16, quad, fb, acc);
  for (int tt = 0; tt < 2; ++tt) {
    int f0 = fb + tt * 16 + quad * 4;
    float4 bb = *(const float4*)(b2 + f0);
    float bbv[4] = {bb.x, bb.y, bb.z, bb.w};
    for (int et = 0; et < 4; ++et) {
      int row = et * 16 + l16;
      float o[4];
      for (int r = 0; r < 4; ++r) o[r] = acc[tt][et][r] + bbv[r];
      *(uint2*)(e + (size_t)(e0 + row) * 128 + f0) = pack4bf(o);
    }
  }
}

// ---------------- fused GNN edge kernel, MFMA, 64 sorted edges/block --------
__global__ __launch_bounds__(256) void gnn_edge_mfma(
    const float* __restrict__ h, const u16* __restrict__ h16, u16* __restrict__ e,
    const int* __restrict__ src_s, const int* __restrict__ dst_s,
    const u16* __restrict__ Wt_e1, const float* __restrict__ be1,
    const u16* __restrict__ Wt_e2, const float* __restrict__ be2,
    const u16* __restrict__ Wt_n1, const float* __restrict__ bn1,
    const u16* __restrict__ Wt_n2, const float* __restrict__ bn2,
    const float* __restrict__ lng, const float* __restrict__ lnb,
    float* __restrict__ agg)
{
  __shared__ __align__(16) char smem[51456];
  u16* sA = (u16*)smem;                     // xi   (16 KB)
  u16* sB = (u16*)(smem + 16384);           // xj -> t1 -> t2
  u16* sC = (u16*)(smem + 32768);           // e  -> e_new
  float* part_s = (float*)(smem + 49152);   // [4][64]
  float* part_q = (float*)(smem + 50176);   // [4][64]
  int* sDst = (int*)(smem + 51200);         // [64]
  float* msgf = (float*)smem;               // 64x129 f32 overlay (33 KB)

  const int t = threadIdx.x;
  const int e0 = blockIdx.x * 64;
  const int lane = t & 63;
  const int wave = t >> 6;
  const int l16 = lane & 15;
  const int quad = lane >> 4;
  const int fb = wave * 32;

  if (t < 64) sDst[t] = dst_s[e0 + t];

  for (int it = 0; it < 4; ++it) {
    int c = t + it * 256;
    int row = c >> 4, seg = c & 15;
    int di = dst_s[e0 + row];
    int si = src_s[e0 + row];
    us8 vi = *(const us8*)(h16 + (size_t)di * 128 + seg * 8);
    us8 vj = *(const us8*)(h16 + (size_t)si * 128 + seg * 8);
    us8 ve = *(const us8*)(e + (size_t)(e0 + row) * 128 + seg * 8);
    int b = (row << 7) + ((seg ^ (row & 15)) << 3);
    *(us8*)(sA + b) = vi;
    *(us8*)(sB + b) = vj;
    *(us8*)(sC + b) = ve;
  }
  __syncthreads();

  // GEMM1: t1 = relu([xi|xj|e] @ We1 + be1), K = 384
  f32x4 acc[2][4];
  for (int tt = 0; tt < 2; ++tt)
    for (int et = 0; et < 4; ++et) acc[tt][et] = zero4();
  for (int ks = 0; ks < 12; ++ks) {
    const u16* sp = (ks < 4) ? sA : ((ks < 8) ? sB : sC);
    int kg = ks * 32 + quad * 8;
    int kk = kg & 127;
    bf16x8 b0 = ldbf(sp + lad(0 * 16 + l16, kk));
    bf16x8 b1 = ldbf(sp + lad(1 * 16 + l16, kk));
    bf16x8 b2 = ldbf(sp + lad(2 * 16 + l16, kk));
    bf16x8 b3 = ldbf(sp + lad(3 * 16 + l16, kk));
    for (int tt = 0; tt < 2; ++tt) {
      bf16x8 a = ldbf(Wt_e1 + (size_t)(fb + tt * 16 + l16) * 384 + kg);
      acc[tt][0] = __builtin_amdgcn_mfma_f32_16x16x32_bf16(a, b0, acc[tt][0], 0, 0, 0);
      acc[tt][1] = __builtin_amdgcn_mfma_f32_16x16x32_bf16(a, b1, acc[tt][1], 0, 0, 0);
      acc[tt][2] = __builtin_amdgcn_mfma_f32_16x16x32_bf16(a, b2, acc[tt][2], 0, 0, 0);
      acc[tt][3] = __builtin_amdgcn_mfma_f32_16x16x32_bf16(a, b3, acc[tt][3], 0, 0, 0);
    }
  }
  __syncthreads();

  // epilogue1: t1 -> sB
  for (int tt = 0; tt < 2; ++tt) {
    int f0 = fb + tt * 16 + quad * 4;
    float4 bb = *(const float4*)(be1 + f0);
    float bbv[4] = {bb.x, bb.y, bb.z, bb.w};
    for (int et = 0; et < 4; ++et) {
      int row = et * 16 + l16;
      float o[4];
      for (int r = 0; r < 4; ++r) o[r] = fmaxf(acc[tt][et][r] + bbv[r], 0.f);
      *(uint2*)(sB + lad(row, f0)) = pack4bf(o);
    }
  }
  __syncthreads();

  // GEMM2: e_new = e + t1 @ We2 + be2 ; sC := e_new ; lnv = e+e_new in regs
  for (int tt = 0; tt < 2; ++tt)
    for (int et = 0; et < 4; ++et) acc[tt][et] = zero4();
  gemm128(sB, Wt_e2, l16, quad, fb, acc);
  float lnv[2][4][4];
  for (int tt = 0; tt < 2; ++tt) {
    int f0 = fb + tt * 16 + quad * 4;
    float4 bb = *(const float4*)(be2 + f0);
    float bbv[4] = {bb.x, bb.y, bb.z, bb.w};
    for (int et = 0; et < 4; ++et) {
      int row = et * 16 + l16;
      float eo[4];
      unpack4bf(*(const uint2*)(sC + lad(row, f0)), eo);
      float en[4];
      for (int r = 0; r < 4; ++r) {
        en[r] = eo[r] + acc[tt][et][r] + bbv[r];
        lnv[tt][et][r] = eo[r] + en[r];
      }
      *(uint2*)(sC + lad(row, f0)) = pack4bf(en);
    }
  }
  for (int et = 0; et < 4; ++et) {
    float s = 0.f, q = 0.f;
    for (int tt = 0; tt < 2; ++tt)
      for (int r = 0; r < 4; ++r) {
        float v = lnv[tt][et][r];
        s += v; q += v * v;
      }
    s += __shfl_xor(s, 16); s += __shfl_xor(s, 32);
    q += __shfl_xor(q, 16); q += __shfl_xor(q, 32);
    if (quad == 0) {
      part_s[wave * 64 + et * 16 + l16] = s;
      part_q[wave * 64 + et * 16 + l16] = q;
    }
  }
  __syncthreads();

  // e-LN apply -> global e (bf16)
  for (int et = 0; et < 4; ++et) {
    int row = et * 16 + l16;
    float s = part_s[row] + part_s[64 + row] + part_s[128 + row] + part_s[192 + row];
    float q = part_q[row] + part_q[64 + row] + part_q[128 + row] + part_q[192 + row];
    float m = s * (1.f / 128.f);
    float var = q * (1.f / 128.f) - m * m;
    float rs = rsqrtf(fmaxf(var, 0.f) + 1e-5f);
    for (int tt = 0; tt < 2; ++tt) {
      int f0 = fb + tt * 16 + quad * 4;
      float4 g4 = *(const float4*)(lng + f0);
      float4 b4 = *(const float4*)(lnb + f0);
      float gv[4] = {g4.x, g4.y, g4.z, g4.w};
      float bv[4] = {b4.x, b4.y, b4.z, b4.w};
      float o[4];
      for (int r = 0; r < 4; ++r)
        o[r] = (lnv[tt][et][r] - m) * rs * gv[r] + bv[r];
      *(uint2*)(e + (size_t)(e0 + row) * 128 + f0) = pack4bf(o);
    }
  }

  // GEMM3: t2 = relu([xi|e_new] @ Wn1 + bn1), K = 256
  for (int tt = 0; tt < 2; ++tt)
    for (int et = 0; et < 4; ++et) acc[tt][et] = zero4();
  for (int ks = 0; ks < 8; ++ks) {
    const u16* sp = (ks < 4) ? sA : sC;
    int kg = ks * 32 + quad * 8;
    int kk = kg & 127;
    bf16x8 b0 = ldbf(sp + lad(0 * 16 + l16, kk));
    bf16x8 b1 = ldbf(sp + lad(1 * 16 + l16, kk));
    bf16x8 b2 = ldbf(sp + lad(2 * 16 + l16, kk));
    bf16x8 b3 = ldbf(sp + lad(3 * 16 + l16, kk));
    for (int tt = 0; tt < 2; ++tt) {
      bf16x8 a = ldbf(Wt_n1 + (size_t)(fb + tt * 16 + l16) * 256 + kg);
      acc[tt][0] = __builtin_amdgcn_mfma_f32_16x16x32_bf16(a, b0, acc[tt][0], 0, 0, 0);
      acc[tt][1] = __builtin_amdgcn_mfma_f32_16x16x32_bf16(a, b1, acc[tt][1], 0, 0, 0);
      acc[tt][2] = __builtin_amdgcn_mfma_f32_16x16x32_bf16(a, b2, acc[tt][2], 0, 0, 0);
      acc[tt][3] = __builtin_amdgcn_mfma_f32_16x16x32_bf16(a, b3, acc[tt][3], 0, 0, 0);
    }
  }
  for (int tt = 0; tt < 2; ++tt) {
    int f0 = fb + tt * 16 + quad * 4;
    float4 bb = *(const float4*)(bn1 + f0);
    float bbv[4] = {bb.x, bb.y, bb.z, bb.w};
    for (int et = 0; et < 4; ++et) {
      int row = et * 16 + l16;
      float o[4];
      for (int r = 0; r < 4; ++r) o[r] = fmaxf(acc[tt][et][r] + bbv[r], 0.f);
      *(uint2*)(sB + lad(row, f0)) = pack4bf(o);
    }
  }
  __syncthreads();

  // GEMM4: msg = xi(f32) + t2 @ Wn2 + bn2 -> LDS msg tile, then segment-sum
  for (int tt = 0; tt < 2; ++tt)
    for (int et = 0; et < 4; ++et) acc[tt][et] = zero4();
  gemm128(sB, Wt_n2, l16, quad, fb, acc);
  __syncthreads();  // tiles dead -> msgf overlay
  for (int tt = 0; tt < 2; ++tt) {
    int f0 = fb + tt * 16 + quad * 4;
    float4 bb = *(const float4*)(bn2 + f0);
    float bbv[4] = {bb.x, bb.y, bb.z, bb.w};
    for (int et = 0; et < 4; ++et) {
      int row = et * 16 + l16;
      int d = sDst[row];
      float4 xi4 = *(const float4*)(h + (size_t)d * 128 + f0);
      float xv[4] = {xi4.x, xi4.y, xi4.z, xi4.w};
      float* mp = msgf + row * 129 + f0;
      for (int r = 0; r < 4; ++r) mp[r] = acc[tt][et][r] + bbv[r] + xv[r];
    }
  }
  __syncthreads();

  // segment reduction over sorted dst
  if (t < 128) {
    int f = t;
    float a = 0.f;
    for (int j = 0; j < 64; ++j) {
      a += msgf[j * 129 + f];
      int dj = sDst[j];
      if (j == 63 || sDst[j + 1] != dj) {
        atomicAdd(&agg[(size_t)dj * 128 + f], a);
        a = 0.f;
      }
    }
  }
}

// node layernorm: h = LN(h + agg) -> h f32 + h16 bf16 ; agg = 0
__global__ void node_ln_kernel(float* h, u16* h16, float* agg,
                               const float* g, const float* b) {
  __shared__ float red[128];
  int f = threadIdx.x;
  int n = blockIdx.x;
  long long base = (long long)n * 128 + f;
  float v = h[base] + agg[base];
  red[f] = v;
  __syncthreads();
  for (int s = 64; s > 0; s >>= 1) {
    if (f < s) red[f] += red[f + s];
    __syncthreads();
  }
  float m = red[0] * (1.0f / 128.0f);
  __syncthreads();
  red[f] = v * v;
  __syncthreads();
  for (int s = 64; s > 0; s >>= 1) {
    if (f < s) red[f] += red[f + s];
    __syncthreads();
  }
  float q = red[0] * (1.0f / 128.0f);
  float var = q - m * m;
  float rs = rsqrtf(fmaxf(var, 0.0f) + 1e-5f);
  float o = (v - m) * rs * g[f] + b[f];
  h[base] = o;
  h16[base] = f2bf(o);
  agg[base] = 0.0f;
}

// decoder: out[n,:2] = mlp(h) - noise[:, :2] ; f32 out
__global__ void decoder_kernel(const float* h, const float* w1, const float* b1,
                               const float* w2, const float* b2,
                               const float* noise, float* out) {
  __shared__ float t1s[128];
  int f = threadIdx.x;
  int n = blockIdx.x;
  float a = b1[f];
  for (int k = 0; k < 128; ++k) a += h[(long long)n * 128 + k] * w1[k * 128 + f];
  t1s[f] = fmaxf(a, 0.0f);
  __syncthreads();
  if (f < 2) {
    float s = b2[f];
    for (int k = 0; k < 128; ++k) s += t1s[k] * w2[k * 2 + f];
    s -= noise[n * 16 + f];
    out[n * 2 + f] = s;
  }
}

extern "C" void kernel_launch(void* const* d_in, const int* in_sizes, int n_in,
                              void* d_out, int out_size, void* d_ws, size_t ws_size,
                              hipStream_t stream) {
  (void)in_sizes; (void)n_in; (void)out_size; (void)ws_size;

  const float* x      = (const float*)d_in[0];
  const float* eattr  = (const float*)d_in[1];
  const int*   eidx   = (const int*)d_in[2];
  const float* nnoise = (const float*)d_in[3];
  const float* enoise = (const float*)d_in[4];
  const float* ne_w1 = (const float*)d_in[5];  const float* ne_b1 = (const float*)d_in[6];
  const float* ne_w2 = (const float*)d_in[7];  const float* ne_b2 = (const float*)d_in[8];
  const float* ee_w1 = (const float*)d_in[9];  const float* ee_b1 = (const float*)d_in[10];
  const float* ee_w2 = (const float*)d_in[11]; const float* ee_b2 = (const float*)d_in[12];
  const float* ge_w1 = (const float*)d_in[13]; const float* ge_b1 = (const float*)d_in[14];
  const float* ge_w2 = (const float*)d_in[15]; const float* ge_b2 = (const float*)d_in[16];
  const float* gn_w1 = (const float*)d_in[17]; const float* gn_b1 = (const float*)d_in[18];
  const float* gn_w2 = (const float*)d_in[19]; const float* gn_b2 = (const float*)d_in[20];
  const float* xlng = (const float*)d_in[21]; const float* xlnb = (const float*)d_in[22];
  const float* elng = (const float*)d_in[23]; const float* elnb = (const float*)d_in[24];
  const float* d_w1 = (const float*)d_in[25]; const float* d_b1 = (const float*)d_in[26];
  const float* d_w2 = (const float*)d_in[27]; const float* d_b2 = (const float*)d_in[28];

  float* out = (float*)d_out;

  // workspace layout (~203 MB of 256 MB)
  char* base = (char*)d_ws;
  size_t off = 0;
  int* idx0 = (int*)(base + off);    off += (size_t)2 * NE * 4;
  int* src_s = (int*)(base + off);   off += (size_t)NE * 4;
  int* dst_s = (int*)(base + off);   off += (size_t)NE * 4;
  int* perm = (int*)(base + off);    off += (size_t)NE * 4;
  int* cnt = (int*)(base + off);     off += (size_t)NN * 4;
  int* cursor = (int*)(base + off);  off += (size_t)NN * 4;
  int* flag = (int*)(base + off);    off += 16;
  float* h = (float*)(base + off);   off += (size_t)NN * 128 * 4;
  u16* h16 = (u16*)(base + off);     off += (size_t)NN * 128 * 2;
  float* agg = (float*)(base + off); off += (size_t)NN * 128 * 4;
  u16* e = (u16*)(base + off);       off += (size_t)NE * 128 * 2;
  u16* Wt_ge1 = (u16*)(base + off);  off += (size_t)384 * 128 * 2;
  u16* Wt_ge2 = (u16*)(base + off);  off += (size_t)128 * 128 * 2;
  u16* Wt_gn1 = (u16*)(base + off);  off += (size_t)256 * 128 * 2;
  u16* Wt_gn2 = (u16*)(base + off);  off += (size_t)128 * 128 * 2;
  u16* Wt_ee2 = (u16*)(base + off);  off += (size_t)128 * 128 * 2;

  hipStreamCaptureStatus cs = hipStreamCaptureStatusNone;
  hipStreamIsCapturing(stream, &cs);
  const bool dbg = (cs == hipStreamCaptureStatusNone);

  const int* src0 = idx0;
  const int* dst0 = idx0 + NE;

  init_kernel<<<(NN * 128 + 255) / 256, 256, 0, stream>>>(agg, NN * 128, cnt, NN);
  idx_detect_kernel<<<1, 64, 0, stream>>>(eidx, flag);
  idx_prep_kernel<<<(2 * NE + 255) / 256, 256, 0, stream>>>(eidx, flag, idx0);

  // counting sort by dst (once; reused by all layers)
  hist_kernel<<<(NE + 255) / 256, 256, 0, stream>>>(dst0, cnt);
  prefix_kernel<<<1, 1024, 0, stream>>>(cnt, cursor);
  scatter_kernel<<<(NE + 255) / 256, 256, 0, stream>>>(src0, dst0, cursor,
                                                       src_s, dst_s, perm);

  transpose_kernel<<<(384 * 128 + 255) / 256, 256, 0, stream>>>(ge_w1, Wt_ge1, 384);
  transpose_kernel<<<(128 * 128 + 255) / 256, 256, 0, stream>>>(ge_w2, Wt_ge2, 128);
  transpose_kernel<<<(256 * 128 + 255) / 256, 256, 0, stream>>>(gn_w1, Wt_gn1, 256);
  transpose_kernel<<<(128 * 128 + 255) / 256, 256, 0, stream>>>(gn_w2, Wt_gn2, 128);
  transpose_kernel<<<(128 * 128 + 255) / 256, 256, 0, stream>>>(ee_w2, Wt_ee2, 128);

  node_enc_kernel<<<NN, 128, 0, stream>>>(x, nnoise, ne_w1, ne_b1, ne_w2, ne_b2, h, h16);
  edge_enc_mfma<<<NE / 64, 256, 0, stream>>>(eattr, enoise, perm,
                                             ee_w1, ee_b1, Wt_ee2, ee_b2, e);

  for (int l = 0; l < NL; ++l) {
    gnn_edge_mfma<<<NE / 64, 256, 0, stream>>>(h, h16, e, src_s, dst_s,
        Wt_ge1, ge_b1, Wt_ge2, ge_b2, Wt_gn1, gn_b1, Wt_gn2, gn_b2,
        elng + l * 128, elnb + l * 128, agg);
    node_ln_kernel<<<NN, 128, 0, stream>>>(h, h16, agg, xlng + l * 128, xlnb + l * 128);
  }

  decoder_kernel<<<NN, 128, 0, stream>>>(h, d_w1, d_b1, d_w2, d_b2, nnoise, out);

  if (dbg) {
    hipStreamSynchronize(stream);
    float tbuf[6] = {0, 0, 0, 0, 0, 0};
    hipMemcpy(tbuf, h, 16, hipMemcpyDeviceToHost);
    hipMemcpy(tbuf + 4, out, 8, hipMemcpyDeviceToHost);
    fprintf(stderr, "KL r23 eenc-mfma: h[0..3]=%.5g %.5g %.5g %.5g out[0..1]=%.5g %.5g lasterr=%d\n",
            tbuf[0], tbuf[1], tbuf[2], tbuf[3], tbuf[4], tbuf[5], (int)hipGetLastError());
    fflush(stderr);
  }
}